// Round 7
// baseline (424.418 us; speedup 1.0000x reference)
//
#include <hip/hip_runtime.h>
#include <hip/hip_bf16.h>

#define HDIM 256
#define HPDIM 128

typedef short bf8 __attribute__((ext_vector_type(8)));   // 8 bf16 in 4 VGPRs
typedef float f32x4 __attribute__((ext_vector_type(4)));

__device__ inline unsigned pkbf2(float a, float b) {
  float2 f; f.x = a; f.y = b;
  __hip_bfloat162 h = __float22bfloat162_rn(f);          // v_cvt_pk_bf16_f32 (RNE)
  unsigned u; __builtin_memcpy(&u, &h, 4); return u;
}
__device__ inline unsigned short bfbits(float v) {
  __hip_bfloat16 h = __float2bfloat16(v);
  unsigned short u; __builtin_memcpy(&u, &h, 2); return u;
}
__device__ inline uint4 pack8u(float4 a, float4 b) {
  uint4 r;
  r.x = pkbf2(a.x, a.y); r.y = pkbf2(a.z, a.w);
  r.z = pkbf2(b.x, b.y); r.w = pkbf2(b.z, b.w);
  return r;
}
__device__ inline float fast_tanh(float x) {
  float t = __expf(2.0f * x);                 // inf/0 at extremes -> +-1 exact
  return 1.0f - 2.0f * __builtin_amdgcn_rcpf(t + 1.0f);
}

// ---------------- Kernel 0: format weights + transpose msg ----------------
// blocks 0..31: w1/w2/w3 -> bf16 MFMA-B-fragment order:
//   wf[((P*Kt + ks)*64 + lane)*8] holds W[p=P*16+(lane&15)][k=ks*32+(lane>>4)*8 .. +8]
// blocks 32..47: msg[b][h] -> msgTT[(h>>2)*4096 + b*4 + (h&3)]
__global__ __launch_bounds__(256) void k_fmt(
    const float* __restrict__ w1, const float* __restrict__ w2,
    const float* __restrict__ w3, const float* __restrict__ msg,
    short* __restrict__ wf, float* __restrict__ msgTT) {
  __shared__ float T[64][257];
  const int t = threadIdx.x;
  if (blockIdx.x < 32) {
    int u = blockIdx.x * 256 + t;              // 0..8191
    const float* src; short* dst; int row, c, Kt;
    if (u < 4096)      { src = w1; dst = wf;          Kt = 8; row = u >> 5; c = u & 31; }
    else if (u < 6144) { src = w2; dst = wf + 32768;  Kt = 4; row = (u-4096) >> 4; c = (u-4096) & 15; }
    else               { src = w3; dst = wf + 49152;  Kt = 4; row = (u-6144) >> 4; c = (u-6144) & 15; }
    int ks = c >> 2, q = c & 3, Kd = Kt * 32;
    const float* s = src + row * Kd + ks * 32 + q * 8;     // coalesced 32B/thread
    float4 a = *(const float4*)s, b = *(const float4*)(s + 4);
    int P = row >> 4, r16 = row & 15;
    int outl = ((P * Kt + ks) * 64 + q * 16 + r16);
    *(uint4*)(dst + (size_t)outl * 8) = pack8u(a, b);
  } else {
    const int b0 = (blockIdx.x - 32) * 64;
    #pragma unroll 4
    for (int it = 0; it < 16; ++it) {
      int flat = it * 1024 + t * 4;
      int row = flat >> 8, col = flat & 255;
      float4 v = *(const float4*)(msg + (b0 + row) * HDIM + col);
      T[row][col] = v.x; T[row][col+1] = v.y; T[row][col+2] = v.z; T[row][col+3] = v.w;
    }
    __syncthreads();
    const int bloc = t & 63;
    #pragma unroll 4
    for (int it = 0; it < 16; ++it) {
      int g = it * 4 + (t >> 6);
      float4 v; v.x = T[bloc][g*4]; v.y = T[bloc][g*4+1];
                v.z = T[bloc][g*4+2]; v.w = T[bloc][g*4+3];
      *(float4*)(msgTT + (size_t)g * 4096 + (b0 + bloc) * 4) = v;
    }
  }
}

// ---------------- Kernel 1: front MLP -> x3 fragments ---------------------
__global__ __launch_bounds__(256) void k_mlp(
    const float* __restrict__ h0, const float* __restrict__ htv,
    const float* __restrict__ cp, const short* __restrict__ wf,
    short* __restrict__ x3f) {
  __shared__ char hbuf[8192];    // 16 x 256 bf16, swizzled 16B blocks
  __shared__ char xa[4096];      // 16 x 128 bf16, swizzled
  __shared__ char xb[4096];
  const int t = threadIdx.x, wave = t >> 6, lane = t & 63;
  const int r16 = lane & 15, quad = lane >> 4;
  const int b0 = blockIdx.x * 16;
  const float cc = fminf(fmaxf(cp[0], 0.f), 1.f);

  #pragma unroll
  for (int it = 0; it < 2; ++it) {
    int flat = it * 2048 + t * 8;
    int row = flat >> 8, col = flat & 255, kb = col >> 3;
    int gi = (b0 + row) * HDIM + col;
    float4 a = *(const float4*)(h0 + gi);
    float4 b = *(const float4*)(htv + gi);
    float4 va, vb;
    va.x = cc*a.x + (1.f-cc)*b.x; va.y = cc*a.y + (1.f-cc)*b.y;
    va.z = cc*a.z + (1.f-cc)*b.z; va.w = cc*a.w + (1.f-cc)*b.w;
    a = *(const float4*)(h0 + gi + 4); b = *(const float4*)(htv + gi + 4);
    vb.x = cc*a.x + (1.f-cc)*b.x; vb.y = cc*a.y + (1.f-cc)*b.y;
    vb.z = cc*a.z + (1.f-cc)*b.z; vb.w = cc*a.w + (1.f-cc)*b.w;
    *(uint4*)(hbuf + row*512 + ((kb ^ (row & 7)) << 4)) = pack8u(va, vb);
  }
  __syncthreads();

  // layer 1
  {
    f32x4 acc[2] = {};
    #pragma unroll
    for (int ks = 0; ks < 8; ++ks) {
      bf8 af = *(bf8*)(hbuf + r16*512 + (((ks*4 + quad) ^ (r16 & 7)) << 4));
      #pragma unroll
      for (int nt = 0; nt < 2; ++nt) {
        bf8 bw_ = *(const bf8*)(wf + (size_t)(((wave*2 + nt)*8 + ks)*64 + lane)*8);
        acc[nt] = __builtin_amdgcn_mfma_f32_16x16x32_bf16(af, bw_, acc[nt], 0, 0, 0);
      }
    }
    #pragma unroll
    for (int nt = 0; nt < 2; ++nt)
      #pragma unroll
      for (int i = 0; i < 4; ++i) {
        int row = quad*4 + i, col = wave*32 + nt*16 + r16;
        *(unsigned short*)(xa + row*256 + (((col >> 3) ^ (row & 7)) << 4) + ((col & 7) << 1))
            = bfbits(fast_tanh(acc[nt][i]));
      }
  }
  __syncthreads();
  // layer 2
  {
    f32x4 acc[2] = {};
    #pragma unroll
    for (int ks = 0; ks < 4; ++ks) {
      bf8 af = *(bf8*)(xa + r16*256 + (((ks*4 + quad) ^ (r16 & 7)) << 4));
      #pragma unroll
      for (int nt = 0; nt < 2; ++nt) {
        bf8 bw_ = *(const bf8*)(wf + 32768 + (size_t)(((wave*2 + nt)*4 + ks)*64 + lane)*8);
        acc[nt] = __builtin_amdgcn_mfma_f32_16x16x32_bf16(af, bw_, acc[nt], 0, 0, 0);
      }
    }
    #pragma unroll
    for (int nt = 0; nt < 2; ++nt)
      #pragma unroll
      for (int i = 0; i < 4; ++i) {
        int row = quad*4 + i, col = wave*32 + nt*16 + r16;
        *(unsigned short*)(xb + row*256 + (((col >> 3) ^ (row & 7)) << 4) + ((col & 7) << 1))
            = bfbits(fast_tanh(acc[nt][i]));
      }
  }
  __syncthreads();
  // layer 3
  {
    f32x4 acc[2] = {};
    #pragma unroll
    for (int ks = 0; ks < 4; ++ks) {
      bf8 af = *(bf8*)(xb + r16*256 + (((ks*4 + quad) ^ (r16 & 7)) << 4));
      #pragma unroll
      for (int nt = 0; nt < 2; ++nt) {
        bf8 bw_ = *(const bf8*)(wf + 49152 + (size_t)(((wave*2 + nt)*4 + ks)*64 + lane)*8);
        acc[nt] = __builtin_amdgcn_mfma_f32_16x16x32_bf16(af, bw_, acc[nt], 0, 0, 0);
      }
    }
    #pragma unroll
    for (int nt = 0; nt < 2; ++nt)
      #pragma unroll
      for (int i = 0; i < 4; ++i) {
        int row = quad*4 + i, col = wave*32 + nt*16 + r16;
        *(unsigned short*)(xa + row*256 + (((col >> 3) ^ (row & 7)) << 4) + ((col & 7) << 1))
            = bfbits(fast_tanh(acc[nt][i]));
      }
  }
  __syncthreads();
  {
    int ks = t >> 6, l = t & 63, q2 = l >> 4, rr = l & 15;
    uint4 d = *(uint4*)(xa + rr*256 + (((ks*4 + q2) ^ (rr & 7)) << 4));
    *(uint4*)(x3f + (size_t)((blockIdx.x*4 + ks)*64 + l)*8) = d;
  }
}

// ---------------- Kernel 2/3: fused hypernetwork GEMM, pipelined ----------
// Each block: 2 kcols x 256 b; 4 waves each own 64 b (all kcols).
// LDS: [buf 2][kc 2][64 rows][256B swizzled] = 64 KB -> 2 blocks/CU.
// Pipeline: LD(r+1) global->VGPR issues before COMP(r); ST(r+1) after.
template<int PHASE>
__global__ __launch_bounds__(256, 2) void k_hyper(
    const short* __restrict__ x3f, const float* __restrict__ wTT,
    const float* __restrict__ fc4, float* __restrict__ outp) {
  __shared__ char lds[65536];
  const int kp = blockIdx.x;                    // kcol pair: kcols 2kp, 2kp+1
  const int t = threadIdx.x, wave = t >> 6, lane = t & 63;
  const int r16 = lane & 15, quad = lane >> 4;
  const int bw = blockIdx.y * 256 + wave * 64;

  // x3 B-fragments (coalesced), reused for both kcols all rounds
  bf8 xf[4][4];
  #pragma unroll
  for (int nt = 0; nt < 4; ++nt)
    #pragma unroll
    for (int ks = 0; ks < 4; ++ks)
      xf[nt][ks] = *(const bf8*)(x3f +
          (size_t)(((blockIdx.y*16 + wave*4 + nt)*4 + ks)*64 + lane)*8);

  const float* src0 = fc4 + ((size_t)(PHASE ? 65536 : 0) + (size_t)kp * 512) * HPDIM;
  const int srow = t >> 2, scol = (t & 3) * 32;   // staging coords
  float4 ra[2][8];
  float gacc[2][4] = {};

  auto LD = [&](int r) {
    #pragma unroll
    for (int kc = 0; kc < 2; ++kc) {
      const float* s = src0 + ((size_t)(kc*256 + r*64 + srow))*HPDIM + scol;
      #pragma unroll
      for (int j = 0; j < 8; ++j) ra[kc][j] = *(const float4*)(s + 4*j);
    }
  };
  auto ST = [&](int buf) {
    #pragma unroll
    for (int kc = 0; kc < 2; ++kc) {
      char* base = lds + (buf*2 + kc)*16384 + srow*256;
      #pragma unroll
      for (int i = 0; i < 4; ++i) {
        int kb = (t & 3)*4 + i;
        *(uint4*)(base + ((kb ^ (srow & 7)) << 4)) = pack8u(ra[kc][2*i], ra[kc][2*i+1]);
      }
    }
  };
  auto COMP = [&](int r, int buf) {
    #pragma unroll
    for (int htl = 0; htl < 4; ++htl) {
      const int row = htl*16 + r16;
      const int hb = r*16 + htl*4 + quad;          // h>>2 group
      float4 wv[4];
      #pragma unroll
      for (int nt = 0; nt < 4; ++nt)
        wv[nt] = *(const float4*)(wTT + (size_t)hb*4096 + (bw + nt*16 + r16)*4);
      bf8 af[2][4];
      #pragma unroll
      for (int kc = 0; kc < 2; ++kc)
        #pragma unroll
        for (int ks = 0; ks < 4; ++ks)
          af[kc][ks] = *(bf8*)(lds + (buf*2 + kc)*16384 + row*256 +
                               (((ks*4 + quad) ^ (row & 7)) << 4));
      #pragma unroll
      for (int kc = 0; kc < 2; ++kc)
        #pragma unroll
        for (int nt = 0; nt < 4; ++nt) {
          f32x4 acc = {};
          #pragma unroll
          for (int ks = 0; ks < 4; ++ks)
            acc = __builtin_amdgcn_mfma_f32_16x16x32_bf16(af[kc][ks], xf[nt][ks], acc, 0, 0, 0);
          gacc[kc][nt] += acc[0]*wv[nt].x + acc[1]*wv[nt].y + acc[2]*wv[nt].z + acc[3]*wv[nt].w;
        }
    }
  };

  LD(0); ST(0); __syncthreads();
  LD(1); COMP(0, 0); ST(1); __syncthreads();
  LD(2); COMP(1, 1); ST(0); __syncthreads();
  LD(3); COMP(2, 0); ST(1); __syncthreads();
  COMP(3, 1);

  #pragma unroll
  for (int kc = 0; kc < 2; ++kc)
    #pragma unroll
    for (int nt = 0; nt < 4; ++nt) {
      float v = gacc[kc][nt];
      v += __shfl_xor(v, 16);
      v += __shfl_xor(v, 32);
      if (quad == 0) {
        int b = bw + nt*16 + r16;
        int kcol = kp*2 + kc;
        if (PHASE == 0) outp[(size_t)(kcol >> 2)*4096 + b*4 + (kcol & 3)] = fast_tanh(v);
        else            outp[b*HDIM + kcol] = v;
      }
    }
}

extern "C" void kernel_launch(void* const* d_in, const int* in_sizes, int n_in,
                              void* d_out, int out_size, void* d_ws, size_t ws_size,
                              hipStream_t stream) {
  const float* h0  = (const float*)d_in[0];
  const float* htt = (const float*)d_in[1];
  const float* msg = (const float*)d_in[2];
  const float* c   = (const float*)d_in[3];
  const float* w1  = (const float*)d_in[4];
  const float* w2  = (const float*)d_in[5];
  const float* w3  = (const float*)d_in[6];
  const float* w4  = (const float*)d_in[7];
  float* out = (float*)d_out;

  short* x3f  = (short*)d_ws;                              // 256 KB
  float* g1TT = (float*)((char*)d_ws + 262144);            // 1 MB
  float* msgTT= (float*)((char*)d_ws + 262144 + 1048576);  // 1 MB
  short* wf   = (short*)((char*)d_ws + 262144 + 2097152);  // 128 KB

  k_fmt<<<dim3(48), dim3(256), 0, stream>>>(w1, w2, w3, msg, wf, msgTT);
  k_mlp<<<dim3(64), dim3(256), 0, stream>>>(h0, htt, c, wf, x3f);
  k_hyper<0><<<dim3(128, 4), dim3(256), 0, stream>>>(x3f, msgTT, w4, g1TT);
  k_hyper<1><<<dim3(128, 4), dim3(256), 0, stream>>>(x3f, g1TT, w4, out);
}

// Round 8
// 282.861 us; speedup vs baseline: 1.5004x; 1.5004x over previous
//
#include <hip/hip_runtime.h>
#include <hip/hip_bf16.h>

#define HDIM 256
#define HPDIM 128

typedef short bf8 __attribute__((ext_vector_type(8)));   // 8 bf16 in 4 VGPRs
typedef float f32x4 __attribute__((ext_vector_type(4)));

__device__ inline unsigned pkbf2(float a, float b) {
  float2 f; f.x = a; f.y = b;
  __hip_bfloat162 h = __float22bfloat162_rn(f);          // v_cvt_pk_bf16_f32 (RNE)
  unsigned u; __builtin_memcpy(&u, &h, 4); return u;
}
__device__ inline unsigned short bfbits(float v) {
  __hip_bfloat16 h = __float2bfloat16(v);
  unsigned short u; __builtin_memcpy(&u, &h, 2); return u;
}
__device__ inline uint4 pack8u(float4 a, float4 b) {
  uint4 r;
  r.x = pkbf2(a.x, a.y); r.y = pkbf2(a.z, a.w);
  r.z = pkbf2(b.x, b.y); r.w = pkbf2(b.z, b.w);
  return r;
}
__device__ inline bf8 pack8v(float4 a, float4 b) {
  union { bf8 v; uint4 u; } r; r.u = pack8u(a, b); return r.v;
}
__device__ inline float fast_tanh(float x) {
  float t = __expf(2.0f * x);                 // inf/0 at extremes -> +-1 exact
  return 1.0f - 2.0f * __builtin_amdgcn_rcpf(t + 1.0f);
}

// ---------------- Kernel 1: front MLP -> x3 fragments  +  msg transpose ---
// blocks 0..63: MLP, 16 b each; weight B-fragments loaded DIRECTLY from
// w1/w2/w3 (8 consecutive f32 per lane, packed to bf16 in-flight).
// blocks 64..79: msg[b][h] -> msgTT[(h>>2)*4096 + b*4 + (h&3)].
__global__ __launch_bounds__(256) void k_pre(
    const float* __restrict__ h0, const float* __restrict__ htv,
    const float* __restrict__ cp, const float* __restrict__ msg,
    const float* __restrict__ w1, const float* __restrict__ w2,
    const float* __restrict__ w3,
    short* __restrict__ x3f, float* __restrict__ msgTT) {
  __shared__ char lds[66048];
  const int t = threadIdx.x, wave = t >> 6, lane = t & 63;

  if (blockIdx.x >= 64) {
    float* T = (float*)lds;                    // [64][257]
    const int b0 = (blockIdx.x - 64) * 64;
    #pragma unroll 4
    for (int it = 0; it < 16; ++it) {
      int flat = it * 1024 + t * 4;
      int row = flat >> 8, col = flat & 255;
      float4 v = *(const float4*)(msg + (b0 + row) * HDIM + col);
      T[row*257 + col]   = v.x; T[row*257 + col+1] = v.y;
      T[row*257 + col+2] = v.z; T[row*257 + col+3] = v.w;
    }
    __syncthreads();
    const int bloc = t & 63;
    #pragma unroll 4
    for (int it = 0; it < 16; ++it) {
      int g = it * 4 + (t >> 6);               // h-group 0..63
      float4 v; v.x = T[bloc*257 + g*4];   v.y = T[bloc*257 + g*4+1];
                v.z = T[bloc*257 + g*4+2]; v.w = T[bloc*257 + g*4+3];
      *(float4*)(msgTT + (size_t)g * 4096 + (b0 + bloc) * 4) = v;
    }
    return;
  }

  char* hbuf = lds;             // 16 x 256 bf16, swizzled 16B blocks (8KB)
  char* xa   = lds + 8192;      // 16 x 128 bf16, swizzled (4KB)
  char* xb   = lds + 12288;
  const int r16 = lane & 15, quad = lane >> 4;
  const int b0 = blockIdx.x * 16;
  const float cc = fminf(fmaxf(cp[0], 0.f), 1.f);

  #pragma unroll
  for (int it = 0; it < 2; ++it) {
    int flat = it * 2048 + t * 8;
    int row = flat >> 8, col = flat & 255, kb = col >> 3;
    int gi = (b0 + row) * HDIM + col;
    float4 a = *(const float4*)(h0 + gi);
    float4 b = *(const float4*)(htv + gi);
    float4 va, vb;
    va.x = cc*a.x + (1.f-cc)*b.x; va.y = cc*a.y + (1.f-cc)*b.y;
    va.z = cc*a.z + (1.f-cc)*b.z; va.w = cc*a.w + (1.f-cc)*b.w;
    a = *(const float4*)(h0 + gi + 4); b = *(const float4*)(htv + gi + 4);
    vb.x = cc*a.x + (1.f-cc)*b.x; vb.y = cc*a.y + (1.f-cc)*b.y;
    vb.z = cc*a.z + (1.f-cc)*b.z; vb.w = cc*a.w + (1.f-cc)*b.w;
    *(uint4*)(hbuf + row*512 + ((kb ^ (row & 7)) << 4)) = pack8u(va, vb);
  }
  __syncthreads();

  // layer 1: [16 x 256] @ w1^T -> xa
  {
    f32x4 acc[2] = {};
    #pragma unroll
    for (int ks = 0; ks < 8; ++ks) {
      bf8 af = *(bf8*)(hbuf + r16*512 + (((ks*4 + quad) ^ (r16 & 7)) << 4));
      #pragma unroll
      for (int nt = 0; nt < 2; ++nt) {
        const float* wp = w1 + ((wave*2 + nt)*16 + r16)*HDIM + ks*32 + quad*8;
        bf8 bw_ = pack8v(*(const float4*)wp, *(const float4*)(wp + 4));
        acc[nt] = __builtin_amdgcn_mfma_f32_16x16x32_bf16(af, bw_, acc[nt], 0, 0, 0);
      }
    }
    #pragma unroll
    for (int nt = 0; nt < 2; ++nt)
      #pragma unroll
      for (int i = 0; i < 4; ++i) {
        int row = quad*4 + i, col = wave*32 + nt*16 + r16;
        *(unsigned short*)(xa + row*256 + (((col >> 3) ^ (row & 7)) << 4) + ((col & 7) << 1))
            = bfbits(fast_tanh(acc[nt][i]));
      }
  }
  __syncthreads();
  // layer 2: xa @ w2^T -> xb
  {
    f32x4 acc[2] = {};
    #pragma unroll
    for (int ks = 0; ks < 4; ++ks) {
      bf8 af = *(bf8*)(xa + r16*256 + (((ks*4 + quad) ^ (r16 & 7)) << 4));
      #pragma unroll
      for (int nt = 0; nt < 2; ++nt) {
        const float* wp = w2 + ((wave*2 + nt)*16 + r16)*HPDIM + ks*32 + quad*8;
        bf8 bw_ = pack8v(*(const float4*)wp, *(const float4*)(wp + 4));
        acc[nt] = __builtin_amdgcn_mfma_f32_16x16x32_bf16(af, bw_, acc[nt], 0, 0, 0);
      }
    }
    #pragma unroll
    for (int nt = 0; nt < 2; ++nt)
      #pragma unroll
      for (int i = 0; i < 4; ++i) {
        int row = quad*4 + i, col = wave*32 + nt*16 + r16;
        *(unsigned short*)(xb + row*256 + (((col >> 3) ^ (row & 7)) << 4) + ((col & 7) << 1))
            = bfbits(fast_tanh(acc[nt][i]));
      }
  }
  __syncthreads();
  // layer 3: xb @ w3^T -> xa
  {
    f32x4 acc[2] = {};
    #pragma unroll
    for (int ks = 0; ks < 4; ++ks) {
      bf8 af = *(bf8*)(xb + r16*256 + (((ks*4 + quad) ^ (r16 & 7)) << 4));
      #pragma unroll
      for (int nt = 0; nt < 2; ++nt) {
        const float* wp = w3 + ((wave*2 + nt)*16 + r16)*HPDIM + ks*32 + quad*8;
        bf8 bw_ = pack8v(*(const float4*)wp, *(const float4*)(wp + 4));
        acc[nt] = __builtin_amdgcn_mfma_f32_16x16x32_bf16(af, bw_, acc[nt], 0, 0, 0);
      }
    }
    #pragma unroll
    for (int nt = 0; nt < 2; ++nt)
      #pragma unroll
      for (int i = 0; i < 4; ++i) {
        int row = quad*4 + i, col = wave*32 + nt*16 + r16;
        *(unsigned short*)(xa + row*256 + (((col >> 3) ^ (row & 7)) << 4) + ((col & 7) << 1))
            = bfbits(fast_tanh(acc[nt][i]));
      }
  }
  __syncthreads();
  // dump xa -> x3f in B-fragment order (coalesced uint4 per lane)
  {
    int ks = t >> 6, l = t & 63, q2 = l >> 4, rr = l & 15;
    uint4 d = *(uint4*)(xa + rr*256 + (((ks*4 + q2) ^ (rr & 7)) << 4));
    *(uint4*)(x3f + (size_t)((blockIdx.x*4 + ks)*64 + l)*8) = d;
  }
}

// ---------------- Kernel 2/3: fused hypernetwork GEMM --------------------
// PHASE 0: g1TT[k,b] = tanh( sum_h msgTT[h,b] * (fc4[kcol*256+h,:] . x3[b,:]) )
// PHASE 1: out[b,kcol] =     sum_k g1TT[k,b]  * (fc4[65536+kcol*256+k,:] . x3[b,:])
// Grid (256 kcol, 2 y); block = 512 thr = 8 waves, each wave owns 64 b.
// Slab staged in two 128-row halves (32 KB LDS); slab re-read redundancy 2x
// (was 4x). wv double-buffered one ht ahead (covered by 16 MFMAs).
template<int PHASE>
__global__ __launch_bounds__(512, 2) void k_hyper(
    const short* __restrict__ x3f, const float* __restrict__ wTT,
    const float* __restrict__ fc4, float* __restrict__ outp) {
  __shared__ char lds[32768];          // 128 rows x 128 bf16, xor-swizzled
  const int kcol = blockIdx.x;
  const int t = threadIdx.x, wave = t >> 6, lane = t & 63;
  const int r16 = lane & 15, quad = lane >> 4;
  const int bw = blockIdx.y * 512 + wave * 64;

  // x3 B-fragments (coalesced 1KB b128 wave-loads), held whole kernel
  bf8 xf[4][4];
  #pragma unroll
  for (int nt = 0; nt < 4; ++nt)
    #pragma unroll
    for (int ks = 0; ks < 4; ++ks)
      xf[nt][ks] = *(const bf8*)(x3f +
          (size_t)(((blockIdx.y*32 + wave*4 + nt)*4 + ks)*64 + lane)*8);

  const float* src = fc4 + ((size_t)(PHASE ? 65536 : 0) + (size_t)kcol * 256) * HPDIM;
  float gacc[4] = {0.f, 0.f, 0.f, 0.f};
  float4 wv[2][4];

  #pragma unroll 1
  for (int half = 0; half < 2; ++half) {
    // stage 128 rows x 128 f32 -> bf16 LDS (512 thr x 8 f32 x 4 iters)
    #pragma unroll
    for (int it = 0; it < 4; ++it) {
      int flat = it * 4096 + t * 8;
      int row = flat >> 7, kb = t & 15;
      float4 a = *(const float4*)(src + half*16384 + flat);
      float4 b = *(const float4*)(src + half*16384 + flat + 4);
      *(uint4*)(lds + row*256 + ((kb ^ (row & 7)) << 4)) = pack8u(a, b);
    }
    __syncthreads();

    // prefetch wv for ht=0
    {
      const int hb = half*32 + quad;
      #pragma unroll
      for (int nt = 0; nt < 4; ++nt)
        wv[0][nt] = *(const float4*)(wTT + (size_t)hb*4096 + (bw + nt*16 + r16)*4);
    }
    #pragma unroll 2
    for (int ht = 0; ht < 8; ++ht) {
      if (ht < 7) {                           // prefetch next ht's wv
        const int hb = half*32 + (ht+1)*4 + quad;
        #pragma unroll
        for (int nt = 0; nt < 4; ++nt)
          wv[(ht+1)&1][nt] = *(const float4*)(wTT + (size_t)hb*4096 + (bw + nt*16 + r16)*4);
      }
      const int row = ht*16 + r16;
      bf8 af[4];
      #pragma unroll
      for (int ks = 0; ks < 4; ++ks)
        af[ks] = *(bf8*)(lds + row*256 + (((ks*4 + quad) ^ (row & 7)) << 4));
      #pragma unroll
      for (int nt = 0; nt < 4; ++nt) {
        f32x4 acc = {};
        #pragma unroll
        for (int ks = 0; ks < 4; ++ks)
          acc = __builtin_amdgcn_mfma_f32_16x16x32_bf16(af[ks], xf[nt][ks], acc, 0, 0, 0);
        float4 w = wv[ht&1][nt];
        gacc[nt] += acc[0]*w.x + acc[1]*w.y + acc[2]*w.z + acc[3]*w.w;
      }
    }
    __syncthreads();                         // slab reads done before restage
  }

  #pragma unroll
  for (int nt = 0; nt < 4; ++nt) {
    float v = gacc[nt];
    v += __shfl_xor(v, 16);
    v += __shfl_xor(v, 32);
    if (quad == 0) {
      int b = bw + nt*16 + r16;
      if (PHASE == 0) outp[(size_t)(kcol >> 2)*4096 + b*4 + (kcol & 3)] = fast_tanh(v);
      else            outp[b*HDIM + kcol] = v;
    }
  }
}

extern "C" void kernel_launch(void* const* d_in, const int* in_sizes, int n_in,
                              void* d_out, int out_size, void* d_ws, size_t ws_size,
                              hipStream_t stream) {
  const float* h0  = (const float*)d_in[0];
  const float* htt = (const float*)d_in[1];
  const float* msg = (const float*)d_in[2];
  const float* c   = (const float*)d_in[3];
  const float* w1  = (const float*)d_in[4];
  const float* w2  = (const float*)d_in[5];
  const float* w3  = (const float*)d_in[6];
  const float* w4  = (const float*)d_in[7];
  float* out = (float*)d_out;

  short* x3f  = (short*)d_ws;                              // 256 KB
  float* g1TT = (float*)((char*)d_ws + 262144);            // 1 MB
  float* msgTT= (float*)((char*)d_ws + 262144 + 1048576);  // 1 MB

  k_pre<<<dim3(80), dim3(256), 0, stream>>>(h0, htt, c, msg, w1, w2, w3, x3f, msgTT);
  k_hyper<0><<<dim3(256, 2), dim3(512), 0, stream>>>(x3f, msgTT, w4, g1TT);
  k_hyper<1><<<dim3(256, 2), dim3(512), 0, stream>>>(x3f, g1TT, w4, out);
}

// Round 9
// 244.750 us; speedup vs baseline: 1.7341x; 1.1557x over previous
//
#include <hip/hip_runtime.h>
#include <hip/hip_bf16.h>

#define HDIM 256
#define HPDIM 128

typedef short bf8 __attribute__((ext_vector_type(8)));   // 8 bf16 in 4 VGPRs
typedef float f32x4 __attribute__((ext_vector_type(4)));

__device__ inline unsigned pkbf2(float a, float b) {
  float2 f; f.x = a; f.y = b;
  __hip_bfloat162 h = __float22bfloat162_rn(f);          // v_cvt_pk_bf16_f32 (RNE)
  unsigned u; __builtin_memcpy(&u, &h, 4); return u;
}
__device__ inline unsigned short bfbits(float v) {
  __hip_bfloat16 h = __float2bfloat16(v);
  unsigned short u; __builtin_memcpy(&u, &h, 2); return u;
}
__device__ inline uint4 pack8u(float4 a, float4 b) {
  uint4 r;
  r.x = pkbf2(a.x, a.y); r.y = pkbf2(a.z, a.w);
  r.z = pkbf2(b.x, b.y); r.w = pkbf2(b.z, b.w);
  return r;
}
__device__ inline bf8 pack8v(float4 a, float4 b) {
  union { bf8 v; uint4 u; } r; r.u = pack8u(a, b); return r.v;
}
__device__ inline float ubits(unsigned u) {
  union { unsigned u; float f; } v; v.u = u; return v.f;
}
__device__ inline float fast_tanh(float x) {
  float t = __expf(2.0f * x);                 // inf/0 at extremes -> +-1 exact
  return 1.0f - 2.0f * __builtin_amdgcn_rcpf(t + 1.0f);
}

// ---------------- Kernel 1: front MLP -> x3 fragments  +  msg transpose ---
// blocks 0..63: MLP, 16 b each; weight B-fragments loaded DIRECTLY from
// w1/w2/w3 (8 consecutive f32 per lane, packed to bf16 in-flight).
// blocks 64..79: msg[b][h] -> msgT16 bf16 [(h>>2)][b][h&3].
__global__ __launch_bounds__(256) void k_pre(
    const float* __restrict__ h0, const float* __restrict__ htv,
    const float* __restrict__ cp, const float* __restrict__ msg,
    const float* __restrict__ w1, const float* __restrict__ w2,
    const float* __restrict__ w3,
    short* __restrict__ x3f, short* __restrict__ msgT16) {
  __shared__ char lds[66048];
  const int t = threadIdx.x, wave = t >> 6, lane = t & 63;

  if (blockIdx.x >= 64) {
    float* T = (float*)lds;                    // [64][257]
    const int b0 = (blockIdx.x - 64) * 64;
    #pragma unroll 4
    for (int it = 0; it < 16; ++it) {
      int flat = it * 1024 + t * 4;
      int row = flat >> 8, col = flat & 255;
      float4 v = *(const float4*)(msg + (b0 + row) * HDIM + col);
      T[row*257 + col]   = v.x; T[row*257 + col+1] = v.y;
      T[row*257 + col+2] = v.z; T[row*257 + col+3] = v.w;
    }
    __syncthreads();
    const int bloc = t & 63;
    #pragma unroll 4
    for (int it = 0; it < 16; ++it) {
      int g = it * 4 + (t >> 6);               // h-group 0..63
      uint2 pk;
      pk.x = pkbf2(T[bloc*257 + g*4],   T[bloc*257 + g*4+1]);
      pk.y = pkbf2(T[bloc*257 + g*4+2], T[bloc*257 + g*4+3]);
      *(uint2*)(msgT16 + ((size_t)g * 1024 + b0 + bloc) * 4) = pk;
    }
    return;
  }

  char* hbuf = lds;             // 16 x 256 bf16, swizzled 16B blocks (8KB)
  char* xa   = lds + 8192;      // 16 x 128 bf16, swizzled (4KB)
  char* xb   = lds + 12288;
  const int r16 = lane & 15, quad = lane >> 4;
  const int b0 = blockIdx.x * 16;
  const float cc = fminf(fmaxf(cp[0], 0.f), 1.f);

  #pragma unroll
  for (int it = 0; it < 2; ++it) {
    int flat = it * 2048 + t * 8;
    int row = flat >> 8, col = flat & 255, kb = col >> 3;
    int gi = (b0 + row) * HDIM + col;
    float4 a = *(const float4*)(h0 + gi);
    float4 b = *(const float4*)(htv + gi);
    float4 va, vb;
    va.x = cc*a.x + (1.f-cc)*b.x; va.y = cc*a.y + (1.f-cc)*b.y;
    va.z = cc*a.z + (1.f-cc)*b.z; va.w = cc*a.w + (1.f-cc)*b.w;
    a = *(const float4*)(h0 + gi + 4); b = *(const float4*)(htv + gi + 4);
    vb.x = cc*a.x + (1.f-cc)*b.x; vb.y = cc*a.y + (1.f-cc)*b.y;
    vb.z = cc*a.z + (1.f-cc)*b.z; vb.w = cc*a.w + (1.f-cc)*b.w;
    *(uint4*)(hbuf + row*512 + ((kb ^ (row & 7)) << 4)) = pack8u(va, vb);
  }
  __syncthreads();

  // layer 1: [16 x 256] @ w1^T -> xa
  {
    f32x4 acc[2] = {};
    #pragma unroll
    for (int ks = 0; ks < 8; ++ks) {
      bf8 af = *(bf8*)(hbuf + r16*512 + (((ks*4 + quad) ^ (r16 & 7)) << 4));
      #pragma unroll
      for (int nt = 0; nt < 2; ++nt) {
        const float* wp = w1 + ((wave*2 + nt)*16 + r16)*HDIM + ks*32 + quad*8;
        bf8 bw_ = pack8v(*(const float4*)wp, *(const float4*)(wp + 4));
        acc[nt] = __builtin_amdgcn_mfma_f32_16x16x32_bf16(af, bw_, acc[nt], 0, 0, 0);
      }
    }
    #pragma unroll
    for (int nt = 0; nt < 2; ++nt)
      #pragma unroll
      for (int i = 0; i < 4; ++i) {
        int row = quad*4 + i, col = wave*32 + nt*16 + r16;
        *(unsigned short*)(xa + row*256 + (((col >> 3) ^ (row & 7)) << 4) + ((col & 7) << 1))
            = bfbits(fast_tanh(acc[nt][i]));
      }
  }
  __syncthreads();
  // layer 2: xa @ w2^T -> xb
  {
    f32x4 acc[2] = {};
    #pragma unroll
    for (int ks = 0; ks < 4; ++ks) {
      bf8 af = *(bf8*)(xa + r16*256 + (((ks*4 + quad) ^ (r16 & 7)) << 4));
      #pragma unroll
      for (int nt = 0; nt < 2; ++nt) {
        const float* wp = w2 + ((wave*2 + nt)*16 + r16)*HPDIM + ks*32 + quad*8;
        bf8 bw_ = pack8v(*(const float4*)wp, *(const float4*)(wp + 4));
        acc[nt] = __builtin_amdgcn_mfma_f32_16x16x32_bf16(af, bw_, acc[nt], 0, 0, 0);
      }
    }
    #pragma unroll
    for (int nt = 0; nt < 2; ++nt)
      #pragma unroll
      for (int i = 0; i < 4; ++i) {
        int row = quad*4 + i, col = wave*32 + nt*16 + r16;
        *(unsigned short*)(xb + row*256 + (((col >> 3) ^ (row & 7)) << 4) + ((col & 7) << 1))
            = bfbits(fast_tanh(acc[nt][i]));
      }
  }
  __syncthreads();
  // layer 3: xb @ w3^T -> xa
  {
    f32x4 acc[2] = {};
    #pragma unroll
    for (int ks = 0; ks < 4; ++ks) {
      bf8 af = *(bf8*)(xb + r16*256 + (((ks*4 + quad) ^ (r16 & 7)) << 4));
      #pragma unroll
      for (int nt = 0; nt < 2; ++nt) {
        const float* wp = w3 + ((wave*2 + nt)*16 + r16)*HPDIM + ks*32 + quad*8;
        bf8 bw_ = pack8v(*(const float4*)wp, *(const float4*)(wp + 4));
        acc[nt] = __builtin_amdgcn_mfma_f32_16x16x32_bf16(af, bw_, acc[nt], 0, 0, 0);
      }
    }
    #pragma unroll
    for (int nt = 0; nt < 2; ++nt)
      #pragma unroll
      for (int i = 0; i < 4; ++i) {
        int row = quad*4 + i, col = wave*32 + nt*16 + r16;
        *(unsigned short*)(xa + row*256 + (((col >> 3) ^ (row & 7)) << 4) + ((col & 7) << 1))
            = bfbits(fast_tanh(acc[nt][i]));
      }
  }
  __syncthreads();
  // dump xa -> x3f in B-fragment order (coalesced uint4 per lane)
  {
    int ks = t >> 6, l = t & 63, q2 = l >> 4, rr = l & 15;
    uint4 d = *(uint4*)(xa + rr*256 + (((ks*4 + q2) ^ (rr & 7)) << 4));
    *(uint4*)(x3f + (size_t)((blockIdx.x*4 + ks)*64 + l)*8) = d;
  }
}

// ---------------- Kernel 2/3: fused hypernetwork GEMM, NO LDS, NO BARRIERS
// PHASE 0: g1T16[k,b] = tanh( sum_h msgT16[h,b] * (fc4[kcol*256+h,:] . x3[b,:]) )
// PHASE 1: out[b,kcol] =      sum_k g1T16[k,b]  * (fc4[65536+kcol*256+k,:] . x3[b,:])
// Grid (256 kcol, 4 y); block 256 = 4 waves; wave owns 64 b, all 256 h-rows.
// fc4 A-frags loaded straight global->VGPR (32 contiguous B/lane, dense),
// f32->bf16 cvt in-flight; wv is bf16 (uint2/lane, coalesced). The ht loop
// has no __syncthreads, so loads pipeline across iterations via vmcnt(N).
template<int PHASE>
__global__ __launch_bounds__(256) void k_hyper(
    const short* __restrict__ x3f, const short* __restrict__ wT16,
    const float* __restrict__ fc4, float* __restrict__ outp,
    short* __restrict__ outp16) {
  const int kcol = blockIdx.x;
  const int t = threadIdx.x, wave = t >> 6, lane = t & 63;
  const int r16 = lane & 15, quad = lane >> 4;
  const int bw = blockIdx.y * 256 + wave * 64;

  // x3 B-fragments (coalesced 1KB b128 wave-loads), held whole kernel
  bf8 xf[4][4];
  #pragma unroll
  for (int nt = 0; nt < 4; ++nt)
    #pragma unroll
    for (int ks = 0; ks < 4; ++ks)
      xf[nt][ks] = *(const bf8*)(x3f +
          (size_t)(((blockIdx.y*16 + wave*4 + nt)*4 + ks)*64 + lane)*8);

  // lane's fc4 base: row (kcol*256 + r16), cols quad*8..+8 (32 contiguous B)
  const float* src = fc4 + ((size_t)(PHASE ? 65536 : 0) + (size_t)kcol * 256 + r16) * HPDIM + quad * 8;
  float gacc[4] = {0.f, 0.f, 0.f, 0.f};

  #pragma unroll 2
  for (int ht = 0; ht < 16; ++ht) {
    const float* rp = src + (size_t)ht * 16 * HPDIM;
    bf8 af[4];
    #pragma unroll
    for (int ks = 0; ks < 4; ++ks)
      af[ks] = pack8v(*(const float4*)(rp + ks*32), *(const float4*)(rp + ks*32 + 4));
    const int hb = ht*4 + quad;                 // h-group (h>>2)
    #pragma unroll
    for (int nt = 0; nt < 4; ++nt) {
      uint2 wr = *(const uint2*)(wT16 + ((size_t)hb*1024 + bw + nt*16 + r16)*4);
      f32x4 acc = {};
      #pragma unroll
      for (int ks = 0; ks < 4; ++ks)
        acc = __builtin_amdgcn_mfma_f32_16x16x32_bf16(af[ks], xf[nt][ks], acc, 0, 0, 0);
      float f0 = ubits(wr.x << 16), f1 = ubits(wr.x & 0xffff0000u);
      float f2 = ubits(wr.y << 16), f3 = ubits(wr.y & 0xffff0000u);
      gacc[nt] += acc[0]*f0 + acc[1]*f1 + acc[2]*f2 + acc[3]*f3;
    }
  }

  #pragma unroll
  for (int nt = 0; nt < 4; ++nt) {
    float v = gacc[nt];
    v += __shfl_xor(v, 16);
    v += __shfl_xor(v, 32);
    if (quad == 0) {
      int b = bw + nt*16 + r16;
      if (PHASE == 0)
        outp16[((size_t)(kcol >> 2))*4096 + b*4 + (kcol & 3)] = bfbits(fast_tanh(v));
      else
        outp[b*HDIM + kcol] = v;
    }
  }
}

extern "C" void kernel_launch(void* const* d_in, const int* in_sizes, int n_in,
                              void* d_out, int out_size, void* d_ws, size_t ws_size,
                              hipStream_t stream) {
  const float* h0  = (const float*)d_in[0];
  const float* htt = (const float*)d_in[1];
  const float* msg = (const float*)d_in[2];
  const float* c   = (const float*)d_in[3];
  const float* w1  = (const float*)d_in[4];
  const float* w2  = (const float*)d_in[5];
  const float* w3  = (const float*)d_in[6];
  const float* w4  = (const float*)d_in[7];
  float* out = (float*)d_out;

  short* x3f   = (short*)d_ws;                             // 256 KB
  short* g1T16 = (short*)((char*)d_ws + 262144);           // 512 KB bf16 [64][1024][4]
  short* msgT16= (short*)((char*)d_ws + 786432);           // 512 KB bf16 [64][1024][4]

  k_pre<<<dim3(80), dim3(256), 0, stream>>>(h0, htt, c, msg, w1, w2, w3, x3f, msgT16);
  k_hyper<0><<<dim3(256, 4), dim3(256), 0, stream>>>(x3f, msgT16, w4, nullptr, g1T16);
  k_hyper<1><<<dim3(256, 4), dim3(256), 0, stream>>>(x3f, g1T16, w4, out, nullptr);
}

// Round 10
// 191.679 us; speedup vs baseline: 2.2142x; 1.2769x over previous
//
#include <hip/hip_runtime.h>
#include <hip/hip_bf16.h>

#define HDIM 256
#define HPDIM 128

typedef short bf8 __attribute__((ext_vector_type(8)));   // 8 bf16 in 4 VGPRs
typedef float f32x4 __attribute__((ext_vector_type(4)));

__device__ inline unsigned pkbf2(float a, float b) {
  float2 f; f.x = a; f.y = b;
  __hip_bfloat162 h = __float22bfloat162_rn(f);          // v_cvt_pk_bf16_f32 (RNE)
  unsigned u; __builtin_memcpy(&u, &h, 4); return u;
}
__device__ inline unsigned short bfbits(float v) {
  __hip_bfloat16 h = __float2bfloat16(v);
  unsigned short u; __builtin_memcpy(&u, &h, 2); return u;
}
__device__ inline uint4 pack8u(float4 a, float4 b) {
  uint4 r;
  r.x = pkbf2(a.x, a.y); r.y = pkbf2(a.z, a.w);
  r.z = pkbf2(b.x, b.y); r.w = pkbf2(b.z, b.w);
  return r;
}
__device__ inline float ubits(unsigned u) {
  union { unsigned u; float f; } v; v.u = u; return v.f;
}
__device__ inline float fast_tanh(float x) {
  float t = __expf(2.0f * x);                 // inf/0 at extremes -> +-1 exact
  return 1.0f - 2.0f * __builtin_amdgcn_rcpf(t + 1.0f);
}

// ---------------- Kernel 1: front MLP (f32 VALU) + msg transpose ----------
// blocks 0..255: MLP, 4 b each. Thread t: p = t&127, handles 2 of the 4 b.
// Per-thread weight rows read directly from global (latency pipelines over
// 128 independent dwordx4). blocks 256..271: msg -> msgT16 bf16 transpose.
__global__ __launch_bounds__(256) void k_pre(
    const float* __restrict__ h0, const float* __restrict__ htv,
    const float* __restrict__ cp, const float* __restrict__ msg,
    const float* __restrict__ w1, const float* __restrict__ w2,
    const float* __restrict__ w3,
    short* __restrict__ x3f, short* __restrict__ msgT16) {
  const int t = threadIdx.x;

  if (blockIdx.x >= 256) {
    __shared__ float T[64][257];
    const int b0 = (blockIdx.x - 256) * 64;
    #pragma unroll 4
    for (int it = 0; it < 16; ++it) {
      int flat = it * 1024 + t * 4;
      int row = flat >> 8, col = flat & 255;
      float4 v = *(const float4*)(msg + (b0 + row) * HDIM + col);
      T[row][col]   = v.x; T[row][col+1] = v.y;
      T[row][col+2] = v.z; T[row][col+3] = v.w;
    }
    __syncthreads();
    const int bloc = t & 63;
    #pragma unroll 4
    for (int it = 0; it < 16; ++it) {
      int g = it * 4 + (t >> 6);               // h-group 0..63
      uint2 pk;
      pk.x = pkbf2(T[bloc][g*4],   T[bloc][g*4+1]);
      pk.y = pkbf2(T[bloc][g*4+2], T[bloc][g*4+3]);
      *(uint2*)(msgT16 + ((size_t)g * 1024 + b0 + bloc) * 4) = pk;
    }
    return;
  }

  __shared__ float hs[4][260];
  __shared__ float xs[4][132];
  __shared__ float ys[4][132];
  const int b0 = blockIdx.x * 4;
  const float cc = fminf(fmaxf(cp[0], 0.f), 1.f);

  // stage h = cc*h0 + (1-cc)*ht for 4 b (coalesced float4)
  {
    int bi = t >> 6, col = (t & 63) * 4;
    int gi = (b0 + bi) * HDIM + col;
    float4 a = *(const float4*)(h0 + gi);
    float4 b = *(const float4*)(htv + gi);
    hs[bi][col]   = cc*a.x + (1.f-cc)*b.x;
    hs[bi][col+1] = cc*a.y + (1.f-cc)*b.y;
    hs[bi][col+2] = cc*a.z + (1.f-cc)*b.z;
    hs[bi][col+3] = cc*a.w + (1.f-cc)*b.w;
  }
  __syncthreads();

  const int p = t & 127, bsel = t >> 7;
  const int bi0 = bsel * 2, bi1 = bsel * 2 + 1;

  // layer 1: K=256
  {
    const float4* wr = (const float4*)(w1 + p * HDIM);
    float s0 = 0.f, s1 = 0.f;
    #pragma unroll 8
    for (int j = 0; j < 64; ++j) {
      float4 w = wr[j];
      s0 += hs[bi0][4*j]*w.x + hs[bi0][4*j+1]*w.y + hs[bi0][4*j+2]*w.z + hs[bi0][4*j+3]*w.w;
      s1 += hs[bi1][4*j]*w.x + hs[bi1][4*j+1]*w.y + hs[bi1][4*j+2]*w.z + hs[bi1][4*j+3]*w.w;
    }
    xs[bi0][p] = fast_tanh(s0);
    xs[bi1][p] = fast_tanh(s1);
  }
  __syncthreads();
  // layer 2: K=128
  {
    const float4* wr = (const float4*)(w2 + p * HPDIM);
    float s0 = 0.f, s1 = 0.f;
    #pragma unroll 8
    for (int j = 0; j < 32; ++j) {
      float4 w = wr[j];
      s0 += xs[bi0][4*j]*w.x + xs[bi0][4*j+1]*w.y + xs[bi0][4*j+2]*w.z + xs[bi0][4*j+3]*w.w;
      s1 += xs[bi1][4*j]*w.x + xs[bi1][4*j+1]*w.y + xs[bi1][4*j+2]*w.z + xs[bi1][4*j+3]*w.w;
    }
    ys[bi0][p] = fast_tanh(s0);
    ys[bi1][p] = fast_tanh(s1);
  }
  __syncthreads();
  // layer 3: K=128 -> x3 (bf16 fragment layout)
  {
    const float4* wr = (const float4*)(w3 + p * HPDIM);
    float s0 = 0.f, s1 = 0.f;
    #pragma unroll 8
    for (int j = 0; j < 32; ++j) {
      float4 w = wr[j];
      s0 += ys[bi0][4*j]*w.x + ys[bi0][4*j+1]*w.y + ys[bi0][4*j+2]*w.z + ys[bi0][4*j+3]*w.w;
      s1 += ys[bi1][4*j]*w.x + ys[bi1][4*j+1]*w.y + ys[bi1][4*j+2]*w.z + ys[bi1][4*j+3]*w.w;
    }
    // x3f[(((b>>4)*4 + ks)*64 + quad*16 + (b&15))*8 + j], k = p
    int ks = p >> 5, qd = (p >> 3) & 3, jj = p & 7;
    int b_0 = b0 + bi0, b_1 = b0 + bi1;
    x3f[(size_t)((((b_0 >> 4)*4 + ks)*64 + qd*16 + (b_0 & 15)))*8 + jj] = bfbits(fast_tanh(s0));
    x3f[(size_t)((((b_1 >> 4)*4 + ks)*64 + qd*16 + (b_1 & 15)))*8 + jj] = bfbits(fast_tanh(s1));
  }
}

// ---------------- Kernel 2/3: fused hypernetwork GEMM, ONE barrier --------
// PHASE 0: g1T16[k,b] = tanh( sum_h msgT16[h,b] * (fc4[kcol*256+h,:] . x3[b,:]) )
// PHASE 1: out[b,kcol] =      sum_k g1T16[k,b]  * (fc4[65536+kcol*256+k,:] . x3[b,:])
// Grid (256 kcol, 2 y) = 512 blocks, 256 thr, 64 KB LDS (2 blocks/CU).
// Full 256-row slab staged once (bf16, swizzled); after the single barrier
// the slab is read-only and waves free-run the bt x ht MFMA loop with no
// further synchronization. wv bf16 register-double-buffered one ht ahead.
template<int PHASE>
__global__ __launch_bounds__(256) void k_hyper(
    const short* __restrict__ x3f, const short* __restrict__ wT16,
    const float* __restrict__ fc4, float* __restrict__ outp,
    short* __restrict__ outp16) {
  __shared__ char lds[65536];          // 256 rows x 128 bf16, xor-swizzled
  const int kcol = blockIdx.x;
  const int t = threadIdx.x, wave = t >> 6, lane = t & 63;
  const int r16 = lane & 15, quad = lane >> 4;

  // ---- stage full slab (256x128 f32 -> bf16), coalesced dwordx4 pairs ----
  const float* src = fc4 + ((size_t)(PHASE ? 65536 : 0) + (size_t)kcol * 256) * HPDIM;
  #pragma unroll 4
  for (int it = 0; it < 16; ++it) {
    int flat = it * 2048 + t * 8;
    int row = flat >> 7, kb = t & 15;
    float4 a = *(const float4*)(src + flat);
    float4 b = *(const float4*)(src + flat + 4);
    *(uint4*)(lds + row*256 + ((kb ^ (row & 7)) << 4)) = pack8u(a, b);
  }
  __syncthreads();                     // the ONLY barrier

  #pragma unroll 1
  for (int bt = 0; bt < 2; ++bt) {
    const int bw = blockIdx.y * 512 + bt * 256 + wave * 64;
    // x3 B-fragments, coalesced b128 wave-loads
    bf8 xf[4][4];
    #pragma unroll
    for (int nt = 0; nt < 4; ++nt)
      #pragma unroll
      for (int ks = 0; ks < 4; ++ks)
        xf[nt][ks] = *(const bf8*)(x3f +
            (size_t)(((((bw + nt*16) >> 4))*4 + ks)*64 + lane)*8);

    float gacc[4] = {0.f, 0.f, 0.f, 0.f};
    uint2 wv[2][4];
    #pragma unroll
    for (int nt = 0; nt < 4; ++nt)     // prefetch wv for ht=0
      wv[0][nt] = *(const uint2*)(wT16 + ((size_t)quad*1024 + bw + nt*16 + r16)*4);

    #pragma unroll 2
    for (int ht = 0; ht < 16; ++ht) {
      if (ht < 15) {                   // prefetch next ht's wv
        const int hb = (ht+1)*4 + quad;
        #pragma unroll
        for (int nt = 0; nt < 4; ++nt)
          wv[(ht+1)&1][nt] = *(const uint2*)(wT16 + ((size_t)hb*1024 + bw + nt*16 + r16)*4);
      }
      const int row = ht*16 + r16;
      bf8 af[4];
      #pragma unroll
      for (int ks = 0; ks < 4; ++ks)
        af[ks] = *(bf8*)(lds + row*256 + (((ks*4 + quad) ^ (row & 7)) << 4));
      #pragma unroll
      for (int nt = 0; nt < 4; ++nt) {
        f32x4 acc = {};
        #pragma unroll
        for (int ks = 0; ks < 4; ++ks)
          acc = __builtin_amdgcn_mfma_f32_16x16x32_bf16(af[ks], xf[nt][ks], acc, 0, 0, 0);
        uint2 wr = wv[ht&1][nt];
        float f0 = ubits(wr.x << 16), f1 = ubits(wr.x & 0xffff0000u);
        float f2 = ubits(wr.y << 16), f3 = ubits(wr.y & 0xffff0000u);
        gacc[nt] += acc[0]*f0 + acc[1]*f1 + acc[2]*f2 + acc[3]*f3;
      }
    }

    #pragma unroll
    for (int nt = 0; nt < 4; ++nt) {
      float v = gacc[nt];
      v += __shfl_xor(v, 16);
      v += __shfl_xor(v, 32);
      if (quad == 0) {
        int b = bw + nt*16 + r16;
        if (PHASE == 0)
          outp16[((size_t)(kcol >> 2))*4096 + b*4 + (kcol & 3)] = bfbits(fast_tanh(v));
        else
          outp[b*HDIM + kcol] = v;
      }
    }
  }
}

extern "C" void kernel_launch(void* const* d_in, const int* in_sizes, int n_in,
                              void* d_out, int out_size, void* d_ws, size_t ws_size,
                              hipStream_t stream) {
  const float* h0  = (const float*)d_in[0];
  const float* htt = (const float*)d_in[1];
  const float* msg = (const float*)d_in[2];
  const float* c   = (const float*)d_in[3];
  const float* w1  = (const float*)d_in[4];
  const float* w2  = (const float*)d_in[5];
  const float* w3  = (const float*)d_in[6];
  const float* w4  = (const float*)d_in[7];
  float* out = (float*)d_out;

  short* x3f   = (short*)d_ws;                             // 256 KB
  short* g1T16 = (short*)((char*)d_ws + 262144);           // 512 KB bf16
  short* msgT16= (short*)((char*)d_ws + 786432);           // 512 KB bf16

  k_pre<<<dim3(272), dim3(256), 0, stream>>>(h0, htt, c, msg, w1, w2, w3, x3f, msgT16);
  k_hyper<0><<<dim3(256, 2), dim3(256), 0, stream>>>(x3f, msgT16, w4, nullptr, g1T16);
  k_hyper<1><<<dim3(256, 2), dim3(256), 0, stream>>>(x3f, g1T16, w4, out, nullptr);
}